// Round 1
// baseline (896.029 us; speedup 1.0000x reference)
//
#include <hip/hip_runtime.h>

typedef float        f32x4 __attribute__((ext_vector_type(4)));
typedef unsigned int u32x4 __attribute__((ext_vector_type(4)));

#define NJ   8192
#define COUT 32

__device__ __forceinline__ unsigned bfpack2(float lo, float hi) {
  // round-half-up bf16 conversion of two floats, packed into one dword
  unsigned a = (__builtin_bit_cast(unsigned int, lo) + 0x8000u) >> 16;
  unsigned b = (__builtin_bit_cast(unsigned int, hi) + 0x8000u) & 0xffff0000u;
  return a | b;
}

// ---------------- prep: y_m = x_m @ W_m + b_m  -> bf16, MFMA-B fragment layout
// yfrag layout (ushort elems): [branch*2+cb][kstep(256)][lane(64)][elem(8)]
//   B-frag for 16x16x32: lane l holds B[k = (l>>4)*8 + e][col = l&15]
__global__ __launch_bounds__(256) void prep_kernel(
    const float* __restrict__ xi, const float* __restrict__ xj1,
    const float* __restrict__ xk,
    const float* __restrict__ Wi, const float* __restrict__ Wj1,
    const float* __restrict__ Wj2, const float* __restrict__ Wk,
    const float* __restrict__ bi, const float* __restrict__ bj1,
    const float* __restrict__ bj2, const float* __restrict__ bk,
    unsigned short* __restrict__ yfrag)
{
  const int branch = blockIdx.y;
  const float* x = (branch == 0) ? xi : (branch == 3) ? xk : xj1;
  const float* W = (branch == 0) ? Wi : (branch == 1) ? Wj1
                 : (branch == 2) ? Wj2 : Wk;
  const float* bv = (branch == 0) ? bi : (branch == 1) ? bj1
                  : (branch == 2) ? bj2 : bk;

  int idx = blockIdx.x * 256 + threadIdx.x;   // 0 .. 262143
  int j = idx >> 5, c = idx & 31;
  float acc = bv[c];
  #pragma unroll
  for (int q = 0; q < 32; ++q) acc += x[j * 32 + q] * W[q * 32 + c];

  int cb = c >> 4, col = c & 15;
  int ks = j >> 5, kk = j & 31;
  int lane = (kk >> 3) * 16 + col;
  int elem = kk & 7;
  size_t off = ((((size_t)(branch * 2 + cb)) * 256 + ks) * 64 + lane) * 8 + elem;
  yfrag[off] = (unsigned short)((__builtin_bit_cast(unsigned int, acc) + 0x8000u) >> 16);
}

// ---------------- main: partial[branch] = G_branch @ y_branch
// grid (256 m-tiles, 4 branches), block 256 = 4 waves.
// wave (rowblk = w&1, cb = w>>1) owns C tile rows [j0, j0+16) cols [cb*16, cb*16+16)
__global__ __launch_bounds__(256) void merge_kernel(
    const float* __restrict__ G0, const float* __restrict__ G1,
    const float* __restrict__ G2, const float* __restrict__ G3,
    const unsigned short* __restrict__ yfrag,
    float* __restrict__ partial)
{
  const int branch = blockIdx.y;
  const float* __restrict__ G =
      (branch == 0) ? G0 : (branch == 1) ? G1 : (branch == 2) ? G2 : G3;

  const int wave   = threadIdx.x >> 6;
  const int lane   = threadIdx.x & 63;
  const int rowblk = wave & 1;
  const int cb     = wave >> 1;
  const int j0     = blockIdx.x * 32 + rowblk * 16;
  const int r      = lane & 15;   // A row within tile / C col
  const int q      = lane >> 4;   // k-group

  const float* gp = G + (size_t)(j0 + r) * 8192 + q * 8;
  const u32x4* yb = (const u32x4*)yfrag + ((size_t)(branch * 2 + cb) * 256) * 64 + lane;

  f32x4 acc = {0.f, 0.f, 0.f, 0.f};

  #pragma unroll 4
  for (int ks = 0; ks < 256; ++ks) {
    f32x4 a0 = *(const f32x4*)(gp + ks * 32);
    f32x4 a1 = *(const f32x4*)(gp + ks * 32 + 4);
    u32x4 bf = yb[ks * 64];
    u32x4 af;
    af.x = bfpack2(a0.x, a0.y);
    af.y = bfpack2(a0.z, a0.w);
    af.z = bfpack2(a1.x, a1.y);
    af.w = bfpack2(a1.z, a1.w);
    // s_nop covers VALU-write -> MFMA-read hazard (recognizer can't see into asm)
    asm("s_nop 2\n\tv_mfma_f32_16x16x32_bf16 %0, %1, %2, %0"
        : "+v"(acc) : "v"(af), "v"(bf));
  }
  // MFMA-write -> VALU/VMEM-read hazard guard before reading acc
  asm volatile("s_nop 7\n\ts_nop 7\n\ts_nop 7");

  // C/D layout: col = lane&15 (=r), row = (lane>>4)*4 + v  [measured m89/m91]
  float* p = partial + (size_t)branch * (NJ * COUT)
           + (size_t)(j0 + q * 4) * COUT + cb * 16 + r;
  #pragma unroll
  for (int v = 0; v < 4; ++v) p[(size_t)v * COUT] = acc[v];
}

// ---------------- combine: out = relu(p0+p1+p2+p3), float4-vectorized
__global__ __launch_bounds__(256) void combine_kernel(
    const f32x4* __restrict__ partial, f32x4* __restrict__ out)
{
  int idx = blockIdx.x * 256 + threadIdx.x;   // 0 .. 65535
  f32x4 s  = partial[idx];
  f32x4 s1 = partial[idx + 65536];
  f32x4 s2 = partial[idx + 131072];
  f32x4 s3 = partial[idx + 196608];
  s += s1; s += s2; s += s3;
  f32x4 r;
  r.x = fmaxf(s.x, 0.f);
  r.y = fmaxf(s.y, 0.f);
  r.z = fmaxf(s.z, 0.f);
  r.w = fmaxf(s.w, 0.f);
  out[idx] = r;
}

extern "C" void kernel_launch(void* const* d_in, const int* in_sizes, int n_in,
                              void* d_out, int out_size, void* d_ws, size_t ws_size,
                              hipStream_t stream) {
  const float* xi  = (const float*)d_in[0];
  const float* xj1 = (const float*)d_in[1];
  // d_in[2] = xj2 : unused (faithful to reference)
  const float* xk  = (const float*)d_in[3];
  const float* G0  = (const float*)d_in[4];   // Gi2j
  const float* G1  = (const float*)d_in[5];   // Adj2j
  const float* G2  = (const float*)d_in[6];   // coAdj2j
  const float* G3  = (const float*)d_in[7];   // Gk2j
  const float* Wi  = (const float*)d_in[8];
  const float* Wj1 = (const float*)d_in[9];
  const float* Wj2 = (const float*)d_in[10];
  const float* Wk  = (const float*)d_in[11];
  const float* bi  = (const float*)d_in[12];
  const float* bj1 = (const float*)d_in[13];
  const float* bj2 = (const float*)d_in[14];
  const float* bk  = (const float*)d_in[15];

  unsigned short* yfrag = (unsigned short*)d_ws;                       // 2 MB
  float* partial = (float*)((char*)d_ws + (size_t)2 * 1024 * 1024);    // 4 MB

  prep_kernel<<<dim3(1024, 4), 256, 0, stream>>>(
      xi, xj1, xk, Wi, Wj1, Wj2, Wk, bi, bj1, bj2, bk, yfrag);
  merge_kernel<<<dim3(256, 4), 256, 0, stream>>>(G0, G1, G2, G3, yfrag, partial);
  combine_kernel<<<dim3(256), 256, 0, stream>>>((const f32x4*)partial, (f32x4*)d_out);
}